// Round 7
// baseline (835.893 us; speedup 1.0000x reference)
//
#include <hip/hip_runtime.h>

// ConventionalGNN: 3x (GCNConv -> GraphNorm -> ReLU), N=100000 nodes, E=1.6M edges, D=128.
// Hs = dinv*h in bf16; AGG[n] = dinv[n]*(sum Hs[src] + Hs[n]), stored bf16.
// H and AGG are COLUMN-BLOCKED: 8 blocks x 16 cols (32B/row); block p is processed by
// XCD p (blockIdx&7) in the gather -> per-XCD read working set = 3.2MB, L2-resident.
// CSR build: XCD-partitioned count/fill. GEMM: MFMA 16x16x32 bf16 with fused prev-norm.

#define EPS_GN 1e-5f

typedef __attribute__((ext_vector_type(8))) short bf16x8;
typedef __attribute__((ext_vector_type(4))) float f32x4;

__device__ __forceinline__ float blo(unsigned u) { return __uint_as_float(u << 16); }
__device__ __forceinline__ float bhi(unsigned u) { return __uint_as_float(u & 0xffff0000u); }
__device__ __forceinline__ unsigned bf16rne(float f) {
  unsigned u = __float_as_uint(f);
  u += 0x7fff + ((u >> 16) & 1);
  return u >> 16;
}
__device__ __forceinline__ unsigned packbf(float x, float y) {
  return bf16rne(x) | (bf16rne(y) << 16);
}

// ---------------- CSR build ----------------

__global__ __launch_bounds__(256) void k_count_p(const int* __restrict__ dst,
                                                 int* __restrict__ cnt, int E, int N) {
  int p = blockIdx.x & 7;
  int lo = (int)((long long)N * p >> 3), hi = (int)((long long)N * (p + 1) >> 3);
  int stride = (gridDim.x >> 3) * 256;
  for (int e = (blockIdx.x >> 3) * 256 + threadIdx.x; e < E; e += stride) {
    int d = dst[e];
    if (d >= lo && d < hi) atomicAdd(&cnt[d], 1);
  }
}

__global__ __launch_bounds__(256) void k_scan1(const int* __restrict__ cnt,
                                               int* __restrict__ rs,
                                               int* __restrict__ bsum, int N) {
  __shared__ int s[256];
  int t = threadIdx.x;
  int base = blockIdx.x * 1024 + t * 4;
  int c0 = (base + 0 < N) ? cnt[base + 0] : 0;
  int c1 = (base + 1 < N) ? cnt[base + 1] : 0;
  int c2 = (base + 2 < N) ? cnt[base + 2] : 0;
  int c3 = (base + 3 < N) ? cnt[base + 3] : 0;
  int tsum = c0 + c1 + c2 + c3;
  s[t] = tsum;
  __syncthreads();
  for (int off = 1; off < 256; off <<= 1) {
    int v = (t >= off) ? s[t - off] : 0;
    __syncthreads();
    s[t] += v;
    __syncthreads();
  }
  int excl = s[t] - tsum;
  if (t == 255) bsum[blockIdx.x] = s[255];
  int e0 = excl, e1 = e0 + c0, e2 = e1 + c1, e3 = e2 + c2;
  if (base + 0 < N) rs[base + 0] = e0;
  if (base + 1 < N) rs[base + 1] = e1;
  if (base + 2 < N) rs[base + 2] = e2;
  if (base + 3 < N) rs[base + 3] = e3;
}

__global__ __launch_bounds__(256) void k_scan2(const int* __restrict__ bsum,
                                               int* __restrict__ boff, int nblk) {
  __shared__ int s[256];
  int t = threadIdx.x;
  int v0 = (t < nblk) ? bsum[t] : 0;
  s[t] = v0;
  __syncthreads();
  for (int off = 1; off < 256; off <<= 1) {
    int v = (t >= off) ? s[t - off] : 0;
    __syncthreads();
    s[t] += v;
    __syncthreads();
  }
  if (t < nblk) boff[t] = s[t] - v0;
}

// Also zeroes the per-block zero-row (row N) of Hcb every call (ws is re-poisoned).
__global__ __launch_bounds__(256) void k_finalize(const int* __restrict__ cnt,
                                                  const int* __restrict__ boff,
                                                  int* __restrict__ rs,
                                                  int* __restrict__ cursor,
                                                  float* __restrict__ dinv,
                                                  unsigned* __restrict__ Hcb, int N, int E,
                                                  int ROWS) {
  int i = blockIdx.x * 256 + threadIdx.x;
  if (i == 0) rs[N] = E;
  if (i < 64) Hcb[((size_t)(i >> 3) * ROWS + N) * 8 + (i & 7)] = 0u;
  if (i < N) {
    int v = rs[i] + boff[i >> 10];
    rs[i] = v;
    cursor[i] = v;
    dinv[i] = rsqrtf((float)cnt[i] + 1.0f);
  }
}

__global__ __launch_bounds__(256) void k_fill_p(const int* __restrict__ src,
                                                const int* __restrict__ dst,
                                                int* __restrict__ cursor,
                                                int* __restrict__ csr, int E, int N) {
  int p = blockIdx.x & 7;
  int lo = (int)((long long)N * p >> 3), hi = (int)((long long)N * (p + 1) >> 3);
  int stride = (gridDim.x >> 3) * 256;
  for (int e = (blockIdx.x >> 3) * 256 + threadIdx.x; e < E; e += stride) {
    int d = dst[e];
    if (d >= lo && d < hi) {
      int pos = atomicAdd(&cursor[d], 1);
      csr[pos] = src[e];
    }
  }
}

// ---------------- Weight transpose (once per call) ----------------

__global__ __launch_bounds__(256) void k_wt(const float* __restrict__ W12,
                                            unsigned short* __restrict__ WbT) {
  int o = blockIdx.x * 256 + threadIdx.x;  // [0, 2*16384)
  int layer = o >> 14, r = o & 16383;
  int n = r >> 7, k = r & 127;
  WbT[o] = (unsigned short)bf16rne(W12[layer * 16384 + k * 128 + n]);
}

// ---------------- Layer kernels ----------------

// Hs(bf16, col-blocked) = dinv * (X @ W0). 4 rows/block; thread = 1 row x 2 cols.
__global__ __launch_bounds__(256) void k_gemm0(const float* __restrict__ X,
                                               const float* __restrict__ W,
                                               const float* __restrict__ dinv,
                                               unsigned* __restrict__ Hcb, int N, int ROWS) {
  __shared__ float Ws[4 * 128];
  int t = threadIdx.x;
  if (t < 128) {
    Ws[t] = W[t];
    Ws[128 + t] = W[128 + t];
    Ws[256 + t] = W[256 + t];
    Ws[384 + t] = W[384 + t];
  }
  __syncthreads();
  int r = t >> 6, l = t & 63;
  int row = blockIdx.x * 4 + r;
  if (row >= N) return;
  float4 xv = ((const float4*)X)[row];
  float di = dinv[row];
  int c0 = 2 * l, c1 = 2 * l + 1;
  float v0 = xv.x * Ws[c0] + xv.y * Ws[128 + c0] + xv.z * Ws[256 + c0] + xv.w * Ws[384 + c0];
  float v1 = xv.x * Ws[c1] + xv.y * Ws[128 + c1] + xv.z * Ws[256 + c1] + xv.w * Ws[384 + c1];
  Hcb[((size_t)(l >> 3) * ROWS + row) * 8 + (l & 7)] = packbf(di * v0, di * v1);
}

// Hs(bf16, col-blocked) = dinv * (relu(norm(AGGcb)) @ W) via MFMA 16x16x32 bf16.
__global__ __launch_bounds__(256, 4) void k_gemm_mfma(const unsigned* __restrict__ AGGcb,
                                                      const unsigned short* __restrict__ WbT,
                                                      const float* __restrict__ stats,
                                                      const float* __restrict__ bias,
                                                      const float* __restrict__ gamma,
                                                      const float* __restrict__ beta,
                                                      const float* __restrict__ alpha,
                                                      const float* __restrict__ dinv,
                                                      unsigned* __restrict__ Hcb, int N,
                                                      int ROWS, float invN) {
  __shared__ float As[128], Bs[128];
  int t = threadIdx.x;
  if (t < 128) {
    float s1 = stats[t] * invN, s2 = stats[128 + t] * invN;
    float b = bias[t], a = alpha[t], g = gamma[t], be = beta[t];
    float mu = s1 + b;                     // mean of (agg + b)
    float E2 = s2 + 2.f * b * s1 + b * b;  // E[(agg+b)^2]
    float var = E2 - (2.f * a - a * a) * mu * mu;
    float A = g * rsqrtf(var + EPS_GN);
    As[t] = A;
    Bs[t] = be - A * a * mu + A * b;  // normed = A*agg + B
  }
  __syncthreads();
  int wv = t >> 6, l = t & 63;
  int r0 = blockIdx.x * 64 + wv * 16;
  if (r0 >= N) return;
  int m = l & 15, kb = l >> 4;

  f32x4 acc[8];
#pragma unroll
  for (int nt = 0; nt < 8; ++nt) acc[nt] = (f32x4){0.f, 0.f, 0.f, 0.f};

#pragma unroll
  for (int ks = 0; ks < 4; ++ks) {
    int k0 = ks * 32 + kb * 8;
    // A slab: cols k0..k0+7 of row r0+m -> block 2ks+(kb>>1), dword offset (kb&1)*4
    const uint4* pa = (const uint4*)(AGGcb + ((size_t)(2 * ks + (kb >> 1)) * ROWS + r0 + m) * 8 +
                                     (kb & 1) * 4);
    uint4 a_raw = pa[0];
    float4 A0 = *reinterpret_cast<const float4*>(&As[k0]);
    float4 A1 = *reinterpret_cast<const float4*>(&As[k0 + 4]);
    float4 B0 = *reinterpret_cast<const float4*>(&Bs[k0]);
    float4 B1 = *reinterpret_cast<const float4*>(&Bs[k0 + 4]);
    bf16x8 bf[8];
#pragma unroll
    for (int nt = 0; nt < 8; ++nt)
      bf[nt] = *reinterpret_cast<const bf16x8*>(WbT + (size_t)(nt * 16 + m) * 128 + k0);
    float xr[8] = {blo(a_raw.x), bhi(a_raw.x), blo(a_raw.y), bhi(a_raw.y),
                   blo(a_raw.z), bhi(a_raw.z), blo(a_raw.w), bhi(a_raw.w)};
    float Aa[8] = {A0.x, A0.y, A0.z, A0.w, A1.x, A1.y, A1.z, A1.w};
    float Bb[8] = {B0.x, B0.y, B0.z, B0.w, B1.x, B1.y, B1.z, B1.w};
    bf16x8 af;
#pragma unroll
    for (int j = 0; j < 8; ++j) {
      float v = fmaf(Aa[j], xr[j], Bb[j]);
      v = v > 0.f ? v : 0.f;
      af[j] = (short)bf16rne(v);
    }
#pragma unroll
    for (int nt = 0; nt < 8; ++nt)
      acc[nt] = __builtin_amdgcn_mfma_f32_16x16x32_bf16(af, bf[nt], acc[nt], 0, 0, 0);
  }

  float dn[4];
#pragma unroll
  for (int r = 0; r < 4; ++r) dn[r] = dinv[r0 + kb * 4 + r];
  bool even = (l & 1) == 0;
#pragma unroll
  for (int nt = 0; nt < 8; ++nt) {
#pragma unroll
    for (int r = 0; r < 4; ++r) {
      float v = acc[nt][r] * dn[r];
      float pv = __shfl_xor(v, 1);
      if (even) {
        unsigned word = packbf(v, pv);
        Hcb[((size_t)nt * ROWS + r0 + kb * 4 + r) * 8 + (m >> 1)] = word;
      }
    }
  }
}

// Column-blocked gather: partition p = blockIdx&7 (-> XCD p) handles cols [16p,16p+16).
// Wave = 8 node-groups x 8 lanes; group walks its node's edge list, lane owns 2 cols (1 dword).
// Virtual edge j=-1 is the self row; j>=len clamps to zero row N. Depth-4 rotating prefetch.
__global__ __launch_bounds__(256) void k_gather_cb(const unsigned* __restrict__ Hcb,
                                                   const int* __restrict__ rs,
                                                   const int* __restrict__ csr,
                                                   const float* __restrict__ dinv,
                                                   unsigned* __restrict__ AGGcb,
                                                   float* __restrict__ stats, int N, int ROWS) {
  int t = threadIdx.x;
  int wave = t >> 6, lane = t & 63;
  int g = lane >> 3, cl = lane & 7;
  int p = blockIdx.x & 7;
  const unsigned* Hp = Hcb + (size_t)p * ROWS * 8;
  unsigned* Ap = AGGcb + (size_t)p * ROWS * 8;
  int q = blockIdx.x >> 3;
  int nstride = (gridDim.x >> 3) * 32;  // blocks/partition * 4 waves * 8 nodes
  float s1a = 0.f, s2a = 0.f, s1b = 0.f, s2b = 0.f;
  for (int n0 = (q * 4 + wave) * 8; n0 < N; n0 += nstride) {
    int n = n0 + g;  // N % 8 == 0 -> always < N
    int j0 = rs[n], j1 = rs[n + 1];
    int len = j1 - j0;
    int ml = len;
    ml = max(ml, __shfl_xor(ml, 8));
    ml = max(ml, __shfl_xor(ml, 16));
    ml = max(ml, __shfl_xor(ml, 32));
    int cnt = ml + 1;  // wave-uniform iteration count
    float a0 = 0.f, a1 = 0.f;
    auto vsrc = [&](int j) -> int {  // j in [-1, ml)
      int jj = j0 + j;
      jj = min(jj, j1 - 1);
      jj = max(jj, j0);
      int c = csr[jj];
      return (j < 0) ? n : ((j < len) ? c : N);
    };
    unsigned rA = Hp[(size_t)vsrc(-1) * 8 + cl];
    unsigned rB, rC, rD, rE;
    if (cnt > 1) rB = Hp[(size_t)vsrc(0) * 8 + cl];
    if (cnt > 2) rC = Hp[(size_t)vsrc(1) * 8 + cl];
    if (cnt > 3) rD = Hp[(size_t)vsrc(2) * 8 + cl];
    for (int it = 0; it < cnt; ++it) {
      if (it + 4 < cnt) rE = Hp[(size_t)vsrc(it + 3) * 8 + cl];
      a0 += blo(rA);
      a1 += bhi(rA);
      rA = rB;
      rB = rC;
      rC = rD;
      rD = rE;
    }
    float dn = dinv[n];
    float v0 = a0 * dn, v1 = a1 * dn;
    Ap[(size_t)n * 8 + cl] = packbf(v0, v1);  // 8 consecutive nodes -> 256B wave store
    s1a += v0;
    s2a = fmaf(v0, v0, s2a);
    s1b += v1;
    s2b = fmaf(v1, v1, s2b);
  }
  // reduce across groups (same cols, different nodes), then across waves, then atomics.
  s1a += __shfl_xor(s1a, 8);
  s1a += __shfl_xor(s1a, 16);
  s1a += __shfl_xor(s1a, 32);
  s2a += __shfl_xor(s2a, 8);
  s2a += __shfl_xor(s2a, 16);
  s2a += __shfl_xor(s2a, 32);
  s1b += __shfl_xor(s1b, 8);
  s1b += __shfl_xor(s1b, 16);
  s1b += __shfl_xor(s1b, 32);
  s2b += __shfl_xor(s2b, 8);
  s2b += __shfl_xor(s2b, 16);
  s2b += __shfl_xor(s2b, 32);
  __shared__ float sh[4][32];
  if (g == 0) {
    sh[wave][2 * cl] = s1a;
    sh[wave][2 * cl + 1] = s1b;
    sh[wave][16 + 2 * cl] = s2a;
    sh[wave][16 + 2 * cl + 1] = s2b;
  }
  __syncthreads();
  if (t < 32) {
    float v = sh[0][t] + sh[1][t] + sh[2][t] + sh[3][t];
    if (t < 16)
      atomicAdd(&stats[p * 16 + t], v);
    else
      atomicAdd(&stats[128 + p * 16 + (t - 16)], v);
  }
}

// Final standalone norm (layer 2): bf16 col-blocked AGG -> fp32 row-major d_out.
__global__ __launch_bounds__(256) void k_norm(const unsigned* __restrict__ AGGcb,
                                              const float* __restrict__ stats,
                                              const float* __restrict__ bias,
                                              const float* __restrict__ gamma,
                                              const float* __restrict__ beta,
                                              const float* __restrict__ alpha,
                                              float* __restrict__ OUT, int N, int ROWS,
                                              float invN) {
  int i = blockIdx.x * 256 + threadIdx.x;  // 4-col chunk index over row-major out
  if (i >= N * 32) return;
  int row = i >> 5, c4 = i & 31;
  int blk = c4 >> 2, off = (2 * c4) & 7;
  uint2 u = *(const uint2*)(AGGcb + ((size_t)blk * ROWS + row) * 8 + off);
  float vv[4] = {blo(u.x), bhi(u.x), blo(u.y), bhi(u.y)};
  float ov[4];
#pragma unroll
  for (int j = 0; j < 4; ++j) {
    int c = c4 * 4 + j;
    float s1 = stats[c] * invN, s2 = stats[128 + c] * invN;
    float b = bias[c], a = alpha[c], g = gamma[c], be = beta[c];
    float mu = s1 + b;
    float E2 = s2 + 2.f * b * s1 + b * b;
    float var = E2 - (2.f * a - a * a) * mu * mu;
    float A = g * rsqrtf(var + EPS_GN);
    float B = be - A * a * mu + A * b;
    float o = fmaf(A, vv[j], B);
    ov[j] = o > 0.f ? o : 0.f;
  }
  ((float4*)OUT)[i] = make_float4(ov[0], ov[1], ov[2], ov[3]);
}

// ---------------- Launch ----------------

extern "C" void kernel_launch(void* const* d_in, const int* in_sizes, int n_in,
                              void* d_out, int out_size, void* d_ws, size_t ws_size,
                              hipStream_t stream) {
  const float* x = (const float*)d_in[0];
  const int* ei = (const int*)d_in[1];
  const float* W0 = (const float*)d_in[2];
  const float* b0 = (const float*)d_in[3];
  const float* W12 = (const float*)d_in[4];
  const float* b12 = (const float*)d_in[5];
  const float* gamma = (const float*)d_in[6];
  const float* beta = (const float*)d_in[7];
  const float* alpha = (const float*)d_in[8];
  float* out = (float*)d_out;

  int N = in_sizes[0] / 4;
  int E = in_sizes[1] / 2;
  int ROWS = N + 1;
  const int* srcArr = ei;
  const int* dstArr = ei + E;

  char* w = (char*)d_ws;
  auto alloc = [&](size_t bytes) {
    char* p = w;
    w += (bytes + 255) & ~(size_t)255;
    return p;
  };
  int* cnt = (int*)alloc((size_t)N * 4);
  float* stats = (float*)alloc(3 * 256 * 4);  // [layer][sum(128)|sumsq(128)] - adjacent to cnt
  int* rs = (int*)alloc(((size_t)N + 1) * 4);
  int* cursor = (int*)alloc((size_t)N * 4);
  int* bsum = (int*)alloc(512);
  int* boff = (int*)alloc(512);
  unsigned short* WbT = (unsigned short*)alloc(2 * 16384 * 2);  // bf16 W^T, both layers
  int* csr = (int*)alloc(((size_t)E + 8) * 4);                  // src only, padded
  float* dinv = (float*)alloc((size_t)N * 4);
  unsigned* Hcb = (unsigned*)alloc((size_t)ROWS * 64 * 4);      // bf16 Hs, col-blocked
  unsigned* AGGcb = (unsigned*)alloc((size_t)ROWS * 64 * 4);    // bf16 agg, col-blocked

  // zero cnt + all stats (contiguous region)
  size_t zlen = (size_t)((char*)stats - (char*)cnt) + 3 * 256 * 4;
  hipMemsetAsync(cnt, 0, zlen, stream);

  int nblk = (N + 1023) / 1024;
  k_wt<<<128, 256, 0, stream>>>(W12, WbT);
  k_count_p<<<2048, 256, 0, stream>>>(dstArr, cnt, E, N);
  k_scan1<<<nblk, 256, 0, stream>>>(cnt, rs, bsum, N);
  k_scan2<<<1, 256, 0, stream>>>(bsum, boff, nblk);
  k_finalize<<<(N + 255) / 256, 256, 0, stream>>>(cnt, boff, rs, cursor, dinv, Hcb, N, E, ROWS);
  k_fill_p<<<2048, 256, 0, stream>>>(srcArr, dstArr, cursor, csr, E, N);

  float invN = 1.0f / (float)N;
  int gGemm = (N + 63) / 64;

  // Layer 0
  k_gemm0<<<(N + 3) / 4, 256, 0, stream>>>(x, W0, dinv, Hcb, N, ROWS);
  k_gather_cb<<<2048, 256, 0, stream>>>(Hcb, rs, csr, dinv, AGGcb, stats, N, ROWS);
  // Layer 1 (norm of layer 0 fused into A-fragment build)
  k_gemm_mfma<<<gGemm, 256, 0, stream>>>(AGGcb, WbT, stats, b0, gamma, beta, alpha, dinv, Hcb, N,
                                         ROWS, invN);
  k_gather_cb<<<2048, 256, 0, stream>>>(Hcb, rs, csr, dinv, AGGcb, stats + 256, N, ROWS);
  // Layer 2
  k_gemm_mfma<<<gGemm, 256, 0, stream>>>(AGGcb, WbT + 16384, stats + 256, b12, gamma + 128,
                                         beta + 128, alpha + 128, dinv, Hcb, N, ROWS, invN);
  k_gather_cb<<<2048, 256, 0, stream>>>(Hcb, rs, csr, dinv, AGGcb, stats + 512, N, ROWS);
  // Final norm -> out
  k_norm<<<(N * 32 + 255) / 256, 256, 0, stream>>>(AGGcb, stats + 512, b12 + 128, gamma + 256,
                                                   beta + 256, alpha + 256, out, N, ROWS, invN);
}

// Round 8
// 720.115 us; speedup vs baseline: 1.1608x; 1.1608x over previous
//
#include <hip/hip_runtime.h>

// ConventionalGNN: 3x (GCNConv -> GraphNorm -> ReLU), N=100000 nodes, E=1.6M edges, D=128.
// Hs = dinv*h in bf16; AGG[n] = dinv[n]*(sum Hs[src] + Hs[n]), stored bf16.
// H and AGG are COLUMN-BLOCKED: 8 blocks x 16 cols (32B/row); block p is processed by
// XCD p (blockIdx&7) in the gather -> per-XCD read working set = 3.2MB, L2-resident.
// Gather wave = 4 nodes x 8 edge-slots x 2 half-row lanes: dwordx4 per lane, 32 edges
// (1KB) in flight per load instruction, 4-deep rotating prefetch.

#define EPS_GN 1e-5f

typedef __attribute__((ext_vector_type(8))) short bf16x8;
typedef __attribute__((ext_vector_type(4))) float f32x4;

__device__ __forceinline__ float blo(unsigned u) { return __uint_as_float(u << 16); }
__device__ __forceinline__ float bhi(unsigned u) { return __uint_as_float(u & 0xffff0000u); }
__device__ __forceinline__ unsigned bf16rne(float f) {
  unsigned u = __float_as_uint(f);
  u += 0x7fff + ((u >> 16) & 1);
  return u >> 16;
}
__device__ __forceinline__ unsigned packbf(float x, float y) {
  return bf16rne(x) | (bf16rne(y) << 16);
}

// ---------------- CSR build ----------------

__global__ __launch_bounds__(256) void k_count_p(const int* __restrict__ dst,
                                                 int* __restrict__ cnt, int E, int N) {
  int p = blockIdx.x & 7;
  int lo = (int)((long long)N * p >> 3), hi = (int)((long long)N * (p + 1) >> 3);
  int stride = (gridDim.x >> 3) * 256;
  for (int e = (blockIdx.x >> 3) * 256 + threadIdx.x; e < E; e += stride) {
    int d = dst[e];
    if (d >= lo && d < hi) atomicAdd(&cnt[d], 1);
  }
}

__global__ __launch_bounds__(256) void k_scan1(const int* __restrict__ cnt,
                                               int* __restrict__ rs,
                                               int* __restrict__ bsum, int N) {
  __shared__ int s[256];
  int t = threadIdx.x;
  int base = blockIdx.x * 1024 + t * 4;
  int c0 = (base + 0 < N) ? cnt[base + 0] : 0;
  int c1 = (base + 1 < N) ? cnt[base + 1] : 0;
  int c2 = (base + 2 < N) ? cnt[base + 2] : 0;
  int c3 = (base + 3 < N) ? cnt[base + 3] : 0;
  int tsum = c0 + c1 + c2 + c3;
  s[t] = tsum;
  __syncthreads();
  for (int off = 1; off < 256; off <<= 1) {
    int v = (t >= off) ? s[t - off] : 0;
    __syncthreads();
    s[t] += v;
    __syncthreads();
  }
  int excl = s[t] - tsum;
  if (t == 255) bsum[blockIdx.x] = s[255];
  int e0 = excl, e1 = e0 + c0, e2 = e1 + c1, e3 = e2 + c2;
  if (base + 0 < N) rs[base + 0] = e0;
  if (base + 1 < N) rs[base + 1] = e1;
  if (base + 2 < N) rs[base + 2] = e2;
  if (base + 3 < N) rs[base + 3] = e3;
}

__global__ __launch_bounds__(256) void k_scan2(const int* __restrict__ bsum,
                                               int* __restrict__ boff, int nblk) {
  __shared__ int s[256];
  int t = threadIdx.x;
  int v0 = (t < nblk) ? bsum[t] : 0;
  s[t] = v0;
  __syncthreads();
  for (int off = 1; off < 256; off <<= 1) {
    int v = (t >= off) ? s[t - off] : 0;
    __syncthreads();
    s[t] += v;
    __syncthreads();
  }
  if (t < nblk) boff[t] = s[t] - v0;
}

// Also zeroes the per-block zero-row (row N) of Hcb every call (ws is re-poisoned).
__global__ __launch_bounds__(256) void k_finalize(const int* __restrict__ cnt,
                                                  const int* __restrict__ boff,
                                                  int* __restrict__ rs,
                                                  int* __restrict__ cursor,
                                                  float* __restrict__ dinv,
                                                  unsigned* __restrict__ Hcb, int N, int E,
                                                  int ROWS) {
  int i = blockIdx.x * 256 + threadIdx.x;
  if (i == 0) rs[N] = E;
  if (i < 64) Hcb[((size_t)(i >> 3) * ROWS + N) * 8 + (i & 7)] = 0u;
  if (i < N) {
    int v = rs[i] + boff[i >> 10];
    rs[i] = v;
    cursor[i] = v;
    dinv[i] = rsqrtf((float)cnt[i] + 1.0f);
  }
}

__global__ __launch_bounds__(256) void k_fill_p(const int* __restrict__ src,
                                                const int* __restrict__ dst,
                                                int* __restrict__ cursor,
                                                int* __restrict__ csr, int E, int N) {
  int p = blockIdx.x & 7;
  int lo = (int)((long long)N * p >> 3), hi = (int)((long long)N * (p + 1) >> 3);
  int stride = (gridDim.x >> 3) * 256;
  for (int e = (blockIdx.x >> 3) * 256 + threadIdx.x; e < E; e += stride) {
    int d = dst[e];
    if (d >= lo && d < hi) {
      int pos = atomicAdd(&cursor[d], 1);
      csr[pos] = src[e];
    }
  }
}

// ---------------- Weight transpose (once per call) ----------------

__global__ __launch_bounds__(256) void k_wt(const float* __restrict__ W12,
                                            unsigned short* __restrict__ WbT) {
  int o = blockIdx.x * 256 + threadIdx.x;  // [0, 2*16384)
  int layer = o >> 14, r = o & 16383;
  int n = r >> 7, k = r & 127;
  WbT[o] = (unsigned short)bf16rne(W12[layer * 16384 + k * 128 + n]);
}

// ---------------- Layer kernels ----------------

// Hs(bf16, col-blocked) = dinv * (X @ W0). 4 rows/block; thread = 1 row x 2 cols.
__global__ __launch_bounds__(256) void k_gemm0(const float* __restrict__ X,
                                               const float* __restrict__ W,
                                               const float* __restrict__ dinv,
                                               unsigned* __restrict__ Hcb, int N, int ROWS) {
  __shared__ float Ws[4 * 128];
  int t = threadIdx.x;
  if (t < 128) {
    Ws[t] = W[t];
    Ws[128 + t] = W[128 + t];
    Ws[256 + t] = W[256 + t];
    Ws[384 + t] = W[384 + t];
  }
  __syncthreads();
  int r = t >> 6, l = t & 63;
  int row = blockIdx.x * 4 + r;
  if (row >= N) return;
  float4 xv = ((const float4*)X)[row];
  float di = dinv[row];
  int c0 = 2 * l, c1 = 2 * l + 1;
  float v0 = xv.x * Ws[c0] + xv.y * Ws[128 + c0] + xv.z * Ws[256 + c0] + xv.w * Ws[384 + c0];
  float v1 = xv.x * Ws[c1] + xv.y * Ws[128 + c1] + xv.z * Ws[256 + c1] + xv.w * Ws[384 + c1];
  Hcb[((size_t)(l >> 3) * ROWS + row) * 8 + (l & 7)] = packbf(di * v0, di * v1);
}

// Hs(bf16, col-blocked) = dinv * (relu(norm(AGGcb)) @ W) via MFMA 16x16x32 bf16.
__global__ __launch_bounds__(256, 4) void k_gemm_mfma(const unsigned* __restrict__ AGGcb,
                                                      const unsigned short* __restrict__ WbT,
                                                      const float* __restrict__ stats,
                                                      const float* __restrict__ bias,
                                                      const float* __restrict__ gamma,
                                                      const float* __restrict__ beta,
                                                      const float* __restrict__ alpha,
                                                      const float* __restrict__ dinv,
                                                      unsigned* __restrict__ Hcb, int N,
                                                      int ROWS, float invN) {
  __shared__ float As[128], Bs[128];
  int t = threadIdx.x;
  if (t < 128) {
    float s1 = stats[t] * invN, s2 = stats[128 + t] * invN;
    float b = bias[t], a = alpha[t], g = gamma[t], be = beta[t];
    float mu = s1 + b;                     // mean of (agg + b)
    float E2 = s2 + 2.f * b * s1 + b * b;  // E[(agg+b)^2]
    float var = E2 - (2.f * a - a * a) * mu * mu;
    float A = g * rsqrtf(var + EPS_GN);
    As[t] = A;
    Bs[t] = be - A * a * mu + A * b;  // normed = A*agg + B
  }
  __syncthreads();
  int wv = t >> 6, l = t & 63;
  int r0 = blockIdx.x * 64 + wv * 16;
  if (r0 >= N) return;
  int m = l & 15, kb = l >> 4;

  f32x4 acc[8];
#pragma unroll
  for (int nt = 0; nt < 8; ++nt) acc[nt] = (f32x4){0.f, 0.f, 0.f, 0.f};

#pragma unroll
  for (int ks = 0; ks < 4; ++ks) {
    int k0 = ks * 32 + kb * 8;
    // A slab: cols k0..k0+7 of row r0+m -> block 2ks+(kb>>1), dword offset (kb&1)*4
    const uint4* pa = (const uint4*)(AGGcb + ((size_t)(2 * ks + (kb >> 1)) * ROWS + r0 + m) * 8 +
                                     (kb & 1) * 4);
    uint4 a_raw = pa[0];
    float4 A0 = *reinterpret_cast<const float4*>(&As[k0]);
    float4 A1 = *reinterpret_cast<const float4*>(&As[k0 + 4]);
    float4 B0 = *reinterpret_cast<const float4*>(&Bs[k0]);
    float4 B1 = *reinterpret_cast<const float4*>(&Bs[k0 + 4]);
    bf16x8 bf[8];
#pragma unroll
    for (int nt = 0; nt < 8; ++nt)
      bf[nt] = *reinterpret_cast<const bf16x8*>(WbT + (size_t)(nt * 16 + m) * 128 + k0);
    float xr[8] = {blo(a_raw.x), bhi(a_raw.x), blo(a_raw.y), bhi(a_raw.y),
                   blo(a_raw.z), bhi(a_raw.z), blo(a_raw.w), bhi(a_raw.w)};
    float Aa[8] = {A0.x, A0.y, A0.z, A0.w, A1.x, A1.y, A1.z, A1.w};
    float Bb[8] = {B0.x, B0.y, B0.z, B0.w, B1.x, B1.y, B1.z, B1.w};
    bf16x8 af;
#pragma unroll
    for (int j = 0; j < 8; ++j) {
      float v = fmaf(Aa[j], xr[j], Bb[j]);
      v = v > 0.f ? v : 0.f;
      af[j] = (short)bf16rne(v);
    }
#pragma unroll
    for (int nt = 0; nt < 8; ++nt)
      acc[nt] = __builtin_amdgcn_mfma_f32_16x16x32_bf16(af, bf[nt], acc[nt], 0, 0, 0);
  }

  float dn[4];
#pragma unroll
  for (int r = 0; r < 4; ++r) dn[r] = dinv[r0 + kb * 4 + r];
  bool even = (l & 1) == 0;
#pragma unroll
  for (int nt = 0; nt < 8; ++nt) {
#pragma unroll
    for (int r = 0; r < 4; ++r) {
      float v = acc[nt][r] * dn[r];
      float pv = __shfl_xor(v, 1);
      if (even) {
        unsigned word = packbf(v, pv);
        Hcb[((size_t)nt * ROWS + r0 + kb * 4 + r) * 8 + (m >> 1)] = word;
      }
    }
  }
}

// Column-blocked gather v2: partition p = blockIdx&7 (-> XCD p) handles cols [16p,16p+16).
// Wave = 4 nodes (g=l>>4) x 8 edge-slots (e=(l>>1)&7) x 2 half-rows (h=l&1).
// Lane loads uint4 (16B): 32 edges/1KB in flight per load instruction. Virtual edge
// j = b*8+e-1: j=-1 self row, j>=len zero row N. 4-deep rotating prefetch.
// Combine across edge-slots via shfl_xor(2,4,8); e==0 lanes pack+store 16B per half-row.
__global__ __launch_bounds__(256) void k_gather_cb(const unsigned* __restrict__ Hcb,
                                                   const int* __restrict__ rs,
                                                   const int* __restrict__ csr,
                                                   const float* __restrict__ dinv,
                                                   unsigned* __restrict__ AGGcb,
                                                   float* __restrict__ stats, int N, int ROWS) {
  int t = threadIdx.x;
  int wave = t >> 6, lane = t & 63;
  int g = lane >> 4, e = (lane >> 1) & 7, h = lane & 1;
  int p = blockIdx.x & 7;
  const uint4* Hp4 = (const uint4*)(Hcb + (size_t)p * ROWS * 8);
  uint4* Ap4 = (uint4*)(AGGcb + (size_t)p * ROWS * 8);
  int q = blockIdx.x >> 3;
  int nstride = (gridDim.x >> 3) * 16;  // blocks/partition * 4 waves * 4 nodes
  float s1acc[8], s2acc[8];
#pragma unroll
  for (int i = 0; i < 8; ++i) s1acc[i] = s2acc[i] = 0.f;

  for (int n0 = (q * 4 + wave) * 4; n0 < N; n0 += nstride) {
    int n = n0 + g;  // N % 4 == 0 -> n < N
    int j0 = rs[n], j1 = rs[n + 1];
    int len = j1 - j0;
    int nb = (len + 8) >> 3;  // ceil((len+1)/8) batches
    int ml = nb;
    ml = max(ml, __shfl_xor(ml, 16));
    ml = max(ml, __shfl_xor(ml, 32));  // wave-uniform batch count (max over 4 nodes)
    float acc[8];
#pragma unroll
    for (int i = 0; i < 8; ++i) acc[i] = 0.f;

    auto ld = [&](int b) -> uint4 {
      int j = b * 8 + e - 1;
      int jj = j0 + j;
      jj = min(jj, j1 - 1);
      jj = max(jj, j0);
      int c = csr[jj];
      int r = (j < 0) ? n : ((j < len) ? c : N);
      return Hp4[(size_t)r * 2 + h];
    };

    uint4 rA = ld(0);
    uint4 rB, rC, rD, rE;
    if (ml > 1) rB = ld(1);
    if (ml > 2) rC = ld(2);
    if (ml > 3) rD = ld(3);
    for (int b = 0; b < ml; ++b) {
      if (b + 4 < ml) rE = ld(b + 4);
      unsigned uu[4] = {rA.x, rA.y, rA.z, rA.w};
#pragma unroll
      for (int i = 0; i < 4; ++i) {
        acc[2 * i] += blo(uu[i]);
        acc[2 * i + 1] += bhi(uu[i]);
      }
      rA = rB;
      rB = rC;
      rC = rD;
      rD = rE;
    }
    // reduce across the 8 edge-slots (lane bits 1..3)
#pragma unroll
    for (int i = 0; i < 8; ++i) {
      acc[i] += __shfl_xor(acc[i], 2);
      acc[i] += __shfl_xor(acc[i], 4);
      acc[i] += __shfl_xor(acc[i], 8);
    }
    if (e == 0) {
      float dn = dinv[n];
      float v[8];
      uint4 wv;
      unsigned* wp = (unsigned*)&wv;
#pragma unroll
      for (int i = 0; i < 8; ++i) v[i] = acc[i] * dn;
#pragma unroll
      for (int i = 0; i < 4; ++i) wp[i] = packbf(v[2 * i], v[2 * i + 1]);
      Ap4[(size_t)n * 2 + h] = wv;
#pragma unroll
      for (int i = 0; i < 8; ++i) {
        s1acc[i] += v[i];
        s2acc[i] = fmaf(v[i], v[i], s2acc[i]);
      }
    }
  }
  // stats: reduce across nodes/groups (lane bits 4,5); lanes 0 (h=0) and 1 (h=1) hold sums.
#pragma unroll
  for (int i = 0; i < 8; ++i) {
    s1acc[i] += __shfl_xor(s1acc[i], 16);
    s1acc[i] += __shfl_xor(s1acc[i], 32);
    s2acc[i] += __shfl_xor(s2acc[i], 16);
    s2acc[i] += __shfl_xor(s2acc[i], 32);
  }
  __shared__ float sh[4][32];
  if (lane < 2) {
#pragma unroll
    for (int i = 0; i < 8; ++i) {
      sh[wave][h * 8 + i] = s1acc[i];
      sh[wave][16 + h * 8 + i] = s2acc[i];
    }
  }
  __syncthreads();
  if (t < 32) {
    float v = sh[0][t] + sh[1][t] + sh[2][t] + sh[3][t];
    if (t < 16)
      atomicAdd(&stats[p * 16 + t], v);
    else
      atomicAdd(&stats[128 + p * 16 + (t - 16)], v);
  }
}

// Final standalone norm (layer 2): bf16 col-blocked AGG -> fp32 row-major d_out.
__global__ __launch_bounds__(256) void k_norm(const unsigned* __restrict__ AGGcb,
                                              const float* __restrict__ stats,
                                              const float* __restrict__ bias,
                                              const float* __restrict__ gamma,
                                              const float* __restrict__ beta,
                                              const float* __restrict__ alpha,
                                              float* __restrict__ OUT, int N, int ROWS,
                                              float invN) {
  int i = blockIdx.x * 256 + threadIdx.x;  // 4-col chunk index over row-major out
  if (i >= N * 32) return;
  int row = i >> 5, c4 = i & 31;
  int blk = c4 >> 2, off = (2 * c4) & 7;
  uint2 u = *(const uint2*)(AGGcb + ((size_t)blk * ROWS + row) * 8 + off);
  float vv[4] = {blo(u.x), bhi(u.x), blo(u.y), bhi(u.y)};
  float ov[4];
#pragma unroll
  for (int j = 0; j < 4; ++j) {
    int c = c4 * 4 + j;
    float s1 = stats[c] * invN, s2 = stats[128 + c] * invN;
    float b = bias[c], a = alpha[c], g = gamma[c], be = beta[c];
    float mu = s1 + b;
    float E2 = s2 + 2.f * b * s1 + b * b;
    float var = E2 - (2.f * a - a * a) * mu * mu;
    float A = g * rsqrtf(var + EPS_GN);
    float B = be - A * a * mu + A * b;
    float o = fmaf(A, vv[j], B);
    ov[j] = o > 0.f ? o : 0.f;
  }
  ((float4*)OUT)[i] = make_float4(ov[0], ov[1], ov[2], ov[3]);
}

// ---------------- Launch ----------------

extern "C" void kernel_launch(void* const* d_in, const int* in_sizes, int n_in,
                              void* d_out, int out_size, void* d_ws, size_t ws_size,
                              hipStream_t stream) {
  const float* x = (const float*)d_in[0];
  const int* ei = (const int*)d_in[1];
  const float* W0 = (const float*)d_in[2];
  const float* b0 = (const float*)d_in[3];
  const float* W12 = (const float*)d_in[4];
  const float* b12 = (const float*)d_in[5];
  const float* gamma = (const float*)d_in[6];
  const float* beta = (const float*)d_in[7];
  const float* alpha = (const float*)d_in[8];
  float* out = (float*)d_out;

  int N = in_sizes[0] / 4;
  int E = in_sizes[1] / 2;
  int ROWS = N + 1;
  const int* srcArr = ei;
  const int* dstArr = ei + E;

  char* w = (char*)d_ws;
  auto alloc = [&](size_t bytes) {
    char* p = w;
    w += (bytes + 255) & ~(size_t)255;
    return p;
  };
  int* cnt = (int*)alloc((size_t)N * 4);
  float* stats = (float*)alloc(3 * 256 * 4);  // [layer][sum(128)|sumsq(128)] - adjacent to cnt
  int* rs = (int*)alloc(((size_t)N + 1) * 4);
  int* cursor = (int*)alloc((size_t)N * 4);
  int* bsum = (int*)alloc(512);
  int* boff = (int*)alloc(512);
  unsigned short* WbT = (unsigned short*)alloc(2 * 16384 * 2);  // bf16 W^T, both layers
  int* csr = (int*)alloc(((size_t)E + 8) * 4);                  // src only, padded
  float* dinv = (float*)alloc((size_t)N * 4);
  unsigned* Hcb = (unsigned*)alloc((size_t)ROWS * 64 * 4);      // bf16 Hs, col-blocked
  unsigned* AGGcb = (unsigned*)alloc((size_t)ROWS * 64 * 4);    // bf16 agg, col-blocked

  // zero cnt + all stats (contiguous region)
  size_t zlen = (size_t)((char*)stats - (char*)cnt) + 3 * 256 * 4;
  hipMemsetAsync(cnt, 0, zlen, stream);

  int nblk = (N + 1023) / 1024;
  k_wt<<<128, 256, 0, stream>>>(W12, WbT);
  k_count_p<<<2048, 256, 0, stream>>>(dstArr, cnt, E, N);
  k_scan1<<<nblk, 256, 0, stream>>>(cnt, rs, bsum, N);
  k_scan2<<<1, 256, 0, stream>>>(bsum, boff, nblk);
  k_finalize<<<(N + 255) / 256, 256, 0, stream>>>(cnt, boff, rs, cursor, dinv, Hcb, N, E, ROWS);
  k_fill_p<<<2048, 256, 0, stream>>>(srcArr, dstArr, cursor, csr, E, N);

  float invN = 1.0f / (float)N;
  int gGemm = (N + 63) / 64;

  // Layer 0
  k_gemm0<<<(N + 3) / 4, 256, 0, stream>>>(x, W0, dinv, Hcb, N, ROWS);
  k_gather_cb<<<2048, 256, 0, stream>>>(Hcb, rs, csr, dinv, AGGcb, stats, N, ROWS);
  // Layer 1 (norm of layer 0 fused into A-fragment build)
  k_gemm_mfma<<<gGemm, 256, 0, stream>>>(AGGcb, WbT, stats, b0, gamma, beta, alpha, dinv, Hcb, N,
                                         ROWS, invN);
  k_gather_cb<<<2048, 256, 0, stream>>>(Hcb, rs, csr, dinv, AGGcb, stats + 256, N, ROWS);
  // Layer 2
  k_gemm_mfma<<<gGemm, 256, 0, stream>>>(AGGcb, WbT + 16384, stats + 256, b12, gamma + 128,
                                         beta + 128, alpha + 128, dinv, Hcb, N, ROWS, invN);
  k_gather_cb<<<2048, 256, 0, stream>>>(Hcb, rs, csr, dinv, AGGcb, stats + 512, N, ROWS);
  // Final norm -> out
  k_norm<<<(N * 32 + 255) / 256, 256, 0, stream>>>(AGGcb, stats + 512, b12 + 128, gamma + 256,
                                                   beta + 256, alpha + 256, out, N, ROWS, invN);
}

// Round 9
// 696.762 us; speedup vs baseline: 1.1997x; 1.0335x over previous
//
#include <hip/hip_runtime.h>

// ConventionalGNN: 3x (GCNConv -> GraphNorm -> ReLU), N=100000 nodes, E=1.6M edges, D=128.
// Hs = dinv*h in bf16; AGG[n] = dinv[n]*(sum Hs[src] + Hs[n]), stored bf16.
// H and AGG are COLUMN-BLOCKED: 8 blocks x 16 cols (32B/row); block p -> XCD p (blockIdx&7),
// per-XCD gather working set = 3.2MB, L2-resident.
// PADDED CSR: each node's slot list = [self, edges..., pad(N)...] rounded to 8 slots ->
// gather inner loop has no clamp chain (one cndmask), unconditional csr pointer walk,
// csr prefetched 2 batches ahead of H (ping-pong, no ring rotation movs).

#define EPS_GN 1e-5f

typedef __attribute__((ext_vector_type(8))) short bf16x8;
typedef __attribute__((ext_vector_type(4))) float f32x4;

__device__ __forceinline__ float blo(unsigned u) { return __uint_as_float(u << 16); }
__device__ __forceinline__ float bhi(unsigned u) { return __uint_as_float(u & 0xffff0000u); }
__device__ __forceinline__ unsigned bf16rne(float f) {
  unsigned u = __float_as_uint(f);
  u += 0x7fff + ((u >> 16) & 1);
  return u >> 16;
}
__device__ __forceinline__ unsigned packbf(float x, float y) {
  return bf16rne(x) | (bf16rne(y) << 16);
}

// ---------------- CSR build ----------------

__global__ __launch_bounds__(256) void k_count_p(const int* __restrict__ dst,
                                                 int* __restrict__ cnt, int E, int N) {
  int p = blockIdx.x & 7;
  int lo = (int)((long long)N * p >> 3), hi = (int)((long long)N * (p + 1) >> 3);
  int stride = (gridDim.x >> 3) * 256;
  for (int e = (blockIdx.x >> 3) * 256 + threadIdx.x; e < E; e += stride) {
    int d = dst[e];
    if (d >= lo && d < hi) atomicAdd(&cnt[d], 1);
  }
}

// Scan of PADDED slot counts pc = (cnt+8)&~7 (self + edges + pad to 8).
__global__ __launch_bounds__(256) void k_scan1(const int* __restrict__ cnt,
                                               int* __restrict__ rs,
                                               int* __restrict__ bsum, int N) {
  __shared__ int s[256];
  int t = threadIdx.x;
  int base = blockIdx.x * 1024 + t * 4;
  int c0 = (base + 0 < N) ? ((cnt[base + 0] + 8) & ~7) : 0;
  int c1 = (base + 1 < N) ? ((cnt[base + 1] + 8) & ~7) : 0;
  int c2 = (base + 2 < N) ? ((cnt[base + 2] + 8) & ~7) : 0;
  int c3 = (base + 3 < N) ? ((cnt[base + 3] + 8) & ~7) : 0;
  int tsum = c0 + c1 + c2 + c3;
  s[t] = tsum;
  __syncthreads();
  for (int off = 1; off < 256; off <<= 1) {
    int v = (t >= off) ? s[t - off] : 0;
    __syncthreads();
    s[t] += v;
    __syncthreads();
  }
  int excl = s[t] - tsum;
  if (t == 255) bsum[blockIdx.x] = s[255];
  int e0 = excl, e1 = e0 + c0, e2 = e1 + c1, e3 = e2 + c2;
  if (base + 0 < N) rs[base + 0] = e0;
  if (base + 1 < N) rs[base + 1] = e1;
  if (base + 2 < N) rs[base + 2] = e2;
  if (base + 3 < N) rs[base + 3] = e3;
}

__global__ __launch_bounds__(256) void k_scan2(const int* __restrict__ bsum,
                                               int* __restrict__ boff, int nblk) {
  __shared__ int s[256];
  int t = threadIdx.x;
  int v0 = (t < nblk) ? bsum[t] : 0;
  s[t] = v0;
  __syncthreads();
  for (int off = 1; off < 256; off <<= 1) {
    int v = (t >= off) ? s[t - off] : 0;
    __syncthreads();
    s[t] += v;
    __syncthreads();
  }
  if (t < nblk) boff[t] = s[t] - v0;
}

// Finalize: rs -> padded offsets; cursor = rs+1 (edges after self); dinv; self slot;
// pad slots = N; zero-row N of Hcb; 1024-dword csrp tail = N (safe lookahead).
__global__ __launch_bounds__(256) void k_finalize(const int* __restrict__ cnt,
                                                  const int* __restrict__ boff,
                                                  int* __restrict__ rs,
                                                  int* __restrict__ cursor,
                                                  float* __restrict__ dinv,
                                                  unsigned* __restrict__ Hcb,
                                                  int* __restrict__ csrp, int N, int E,
                                                  int ROWS) {
  __shared__ int sTail;
  int i = blockIdx.x * 256 + threadIdx.x;
  if (i < 64) Hcb[((size_t)(i >> 3) * ROWS + N) * 8 + (i & 7)] = 0u;
  if (i < N) {
    int v = rs[i] + boff[i >> 10];
    int c = cnt[i];
    int pc = (c + 8) & ~7;
    rs[i] = v;
    cursor[i] = v + 1;
    dinv[i] = rsqrtf((float)c + 1.0f);
    csrp[v] = i;  // self slot
    for (int k = v + 1 + c; k < v + pc; ++k) csrp[k] = N;  // pads -> zero row
    if (i == N - 1) {
      rs[N] = v + pc;
      sTail = v + pc;
    }
  }
  __syncthreads();
  if (blockIdx.x == gridDim.x - 1) {
    int base = sTail;
    for (int k = threadIdx.x; k < 1024; k += 256) csrp[base + k] = N;
  }
}

__global__ __launch_bounds__(256) void k_fill_p(const int* __restrict__ src,
                                                const int* __restrict__ dst,
                                                int* __restrict__ cursor,
                                                int* __restrict__ csrp, int E, int N) {
  int p = blockIdx.x & 7;
  int lo = (int)((long long)N * p >> 3), hi = (int)((long long)N * (p + 1) >> 3);
  int stride = (gridDim.x >> 3) * 256;
  for (int e = (blockIdx.x >> 3) * 256 + threadIdx.x; e < E; e += stride) {
    int d = dst[e];
    if (d >= lo && d < hi) {
      int pos = atomicAdd(&cursor[d], 1);
      csrp[pos] = src[e];
    }
  }
}

// ---------------- Weight transpose (once per call) ----------------

__global__ __launch_bounds__(256) void k_wt(const float* __restrict__ W12,
                                            unsigned short* __restrict__ WbT) {
  int o = blockIdx.x * 256 + threadIdx.x;  // [0, 2*16384)
  int layer = o >> 14, r = o & 16383;
  int n = r >> 7, k = r & 127;
  WbT[o] = (unsigned short)bf16rne(W12[layer * 16384 + k * 128 + n]);
}

// ---------------- Layer kernels ----------------

// Hs(bf16, col-blocked) = dinv * (X @ W0). 4 rows/block; thread = 1 row x 2 cols.
__global__ __launch_bounds__(256) void k_gemm0(const float* __restrict__ X,
                                               const float* __restrict__ W,
                                               const float* __restrict__ dinv,
                                               unsigned* __restrict__ Hcb, int N, int ROWS) {
  __shared__ float Ws[4 * 128];
  int t = threadIdx.x;
  if (t < 128) {
    Ws[t] = W[t];
    Ws[128 + t] = W[128 + t];
    Ws[256 + t] = W[256 + t];
    Ws[384 + t] = W[384 + t];
  }
  __syncthreads();
  int r = t >> 6, l = t & 63;
  int row = blockIdx.x * 4 + r;
  if (row >= N) return;
  float4 xv = ((const float4*)X)[row];
  float di = dinv[row];
  int c0 = 2 * l, c1 = 2 * l + 1;
  float v0 = xv.x * Ws[c0] + xv.y * Ws[128 + c0] + xv.z * Ws[256 + c0] + xv.w * Ws[384 + c0];
  float v1 = xv.x * Ws[c1] + xv.y * Ws[128 + c1] + xv.z * Ws[256 + c1] + xv.w * Ws[384 + c1];
  Hcb[((size_t)(l >> 3) * ROWS + row) * 8 + (l & 7)] = packbf(di * v0, di * v1);
}

// Hs(bf16, col-blocked) = dinv * (relu(norm(AGGcb)) @ W) via MFMA 16x16x32 bf16.
__global__ __launch_bounds__(256, 4) void k_gemm_mfma(const unsigned* __restrict__ AGGcb,
                                                      const unsigned short* __restrict__ WbT,
                                                      const float* __restrict__ stats,
                                                      const float* __restrict__ bias,
                                                      const float* __restrict__ gamma,
                                                      const float* __restrict__ beta,
                                                      const float* __restrict__ alpha,
                                                      const float* __restrict__ dinv,
                                                      unsigned* __restrict__ Hcb, int N,
                                                      int ROWS, float invN) {
  __shared__ float As[128], Bs[128];
  int t = threadIdx.x;
  if (t < 128) {
    float s1 = stats[t] * invN, s2 = stats[128 + t] * invN;
    float b = bias[t], a = alpha[t], g = gamma[t], be = beta[t];
    float mu = s1 + b;                     // mean of (agg + b)
    float E2 = s2 + 2.f * b * s1 + b * b;  // E[(agg+b)^2]
    float var = E2 - (2.f * a - a * a) * mu * mu;
    float A = g * rsqrtf(var + EPS_GN);
    As[t] = A;
    Bs[t] = be - A * a * mu + A * b;  // normed = A*agg + B
  }
  __syncthreads();
  int wv = t >> 6, l = t & 63;
  int r0 = blockIdx.x * 64 + wv * 16;
  if (r0 >= N) return;
  int m = l & 15, kb = l >> 4;

  f32x4 acc[8];
#pragma unroll
  for (int nt = 0; nt < 8; ++nt) acc[nt] = (f32x4){0.f, 0.f, 0.f, 0.f};

#pragma unroll
  for (int ks = 0; ks < 4; ++ks) {
    int k0 = ks * 32 + kb * 8;
    const uint4* pa = (const uint4*)(AGGcb + ((size_t)(2 * ks + (kb >> 1)) * ROWS + r0 + m) * 8 +
                                     (kb & 1) * 4);
    uint4 a_raw = pa[0];
    float4 A0 = *reinterpret_cast<const float4*>(&As[k0]);
    float4 A1 = *reinterpret_cast<const float4*>(&As[k0 + 4]);
    float4 B0 = *reinterpret_cast<const float4*>(&Bs[k0]);
    float4 B1 = *reinterpret_cast<const float4*>(&Bs[k0 + 4]);
    bf16x8 bf[8];
#pragma unroll
    for (int nt = 0; nt < 8; ++nt)
      bf[nt] = *reinterpret_cast<const bf16x8*>(WbT + (size_t)(nt * 16 + m) * 128 + k0);
    float xr[8] = {blo(a_raw.x), bhi(a_raw.x), blo(a_raw.y), bhi(a_raw.y),
                   blo(a_raw.z), bhi(a_raw.z), blo(a_raw.w), bhi(a_raw.w)};
    float Aa[8] = {A0.x, A0.y, A0.z, A0.w, A1.x, A1.y, A1.z, A1.w};
    float Bb[8] = {B0.x, B0.y, B0.z, B0.w, B1.x, B1.y, B1.z, B1.w};
    bf16x8 af;
#pragma unroll
    for (int j = 0; j < 8; ++j) {
      float v = fmaf(Aa[j], xr[j], Bb[j]);
      v = v > 0.f ? v : 0.f;
      af[j] = (short)bf16rne(v);
    }
#pragma unroll
    for (int nt = 0; nt < 8; ++nt)
      acc[nt] = __builtin_amdgcn_mfma_f32_16x16x32_bf16(af, bf[nt], acc[nt], 0, 0, 0);
  }

  float dn[4];
#pragma unroll
  for (int r = 0; r < 4; ++r) dn[r] = dinv[r0 + kb * 4 + r];
  bool even = (l & 1) == 0;
#pragma unroll
  for (int nt = 0; nt < 8; ++nt) {
#pragma unroll
    for (int r = 0; r < 4; ++r) {
      float v = acc[nt][r] * dn[r];
      float pv = __shfl_xor(v, 1);
      if (even) {
        unsigned word = packbf(v, pv);
        Hcb[((size_t)nt * ROWS + r0 + kb * 4 + r) * 8 + (m >> 1)] = word;
      }
    }
  }
}

// Column-blocked gather v3 (padded CSR): partition p = blockIdx&7 -> cols [16p,16p+16).
// Wave = 4 nodes (g) x 8 slots (e) x 2 half-rows (h); lane loads uint4 (16B).
// Batch b covers slots b*8+e; per-lane zero-clamp (b<nb ? c : N) replaces all edge logic.
// csr fetched 2 batches ahead of H; H ping-pong (hA/hB), unroll-2, no rotation movs.
__global__ __launch_bounds__(256) void k_gather_cb(const unsigned* __restrict__ Hcb,
                                                   const int* __restrict__ rsp,
                                                   const int* __restrict__ csrp,
                                                   const float* __restrict__ dinv,
                                                   unsigned* __restrict__ AGGcb,
                                                   float* __restrict__ stats, int N, int ROWS) {
  int t = threadIdx.x;
  int wave = t >> 6, lane = t & 63;
  int g = lane >> 4, e = (lane >> 1) & 7, h = lane & 1;
  int p = blockIdx.x & 7;
  const uint4* Hp4 = (const uint4*)(Hcb + (size_t)p * ROWS * 8);
  uint4* Ap4 = (uint4*)(AGGcb + (size_t)p * ROWS * 8);
  int q = blockIdx.x >> 3;
  int nstride = (gridDim.x >> 3) * 16;  // blocks/partition * 4 waves * 4 nodes
  float s1acc[8], s2acc[8];
#pragma unroll
  for (int i = 0; i < 8; ++i) s1acc[i] = s2acc[i] = 0.f;

  for (int n0 = (q * 4 + wave) * 4; n0 < N; n0 += nstride) {
    int n = n0 + g;  // N % 4 == 0 -> n < N
    int j0 = rsp[n], j1 = rsp[n + 1];
    int nb = (j1 - j0) >> 3;  // padded batch count (>= 1)
    int ml = nb;
    ml = max(ml, __shfl_xor(ml, 16));
    ml = max(ml, __shfl_xor(ml, 32));  // wave-uniform batch count
    float acc[8];
#pragma unroll
    for (int i = 0; i < 8; ++i) acc[i] = 0.f;

    const int* cp = csrp + j0 + e;  // lane slot pointer; batch b at cp[b*8]
    auto hload = [&](int c, int b) -> uint4 {
      int ce = (b < nb) ? c : N;  // beyond own batches -> zero row
      return Hp4[(size_t)ce * 2 + h];
    };
    int c0 = cp[0], c1 = cp[8];
    uint4 hA = hload(c0, 0);
    uint4 hB = hload(c1, 1);
    int c2 = cp[16], c3 = cp[24];
    const int* cpp = cp + 32;  // batch 4

    for (int b = 0; b < ml; b += 2) {
      {
        unsigned uu[4] = {hA.x, hA.y, hA.z, hA.w};
#pragma unroll
        for (int i = 0; i < 4; ++i) {
          acc[2 * i] += blo(uu[i]);
          acc[2 * i + 1] += bhi(uu[i]);
        }
      }
      hA = hload(c2, b + 2);
      c2 = cpp[0];
      if (b + 1 < ml) {  // wave-uniform (scalar) branch
        unsigned uu[4] = {hB.x, hB.y, hB.z, hB.w};
#pragma unroll
        for (int i = 0; i < 4; ++i) {
          acc[2 * i] += blo(uu[i]);
          acc[2 * i + 1] += bhi(uu[i]);
        }
        hB = hload(c3, b + 3);
        c3 = cpp[8];
      }
      cpp += 16;
    }
    // reduce across the 8 edge-slots (lane bits 1..3)
#pragma unroll
    for (int i = 0; i < 8; ++i) {
      acc[i] += __shfl_xor(acc[i], 2);
      acc[i] += __shfl_xor(acc[i], 4);
      acc[i] += __shfl_xor(acc[i], 8);
    }
    if (e == 0) {
      float dn = dinv[n];
      float v[8];
      uint4 wv;
      unsigned* wp = (unsigned*)&wv;
#pragma unroll
      for (int i = 0; i < 8; ++i) v[i] = acc[i] * dn;
#pragma unroll
      for (int i = 0; i < 4; ++i) wp[i] = packbf(v[2 * i], v[2 * i + 1]);
      Ap4[(size_t)n * 2 + h] = wv;
#pragma unroll
      for (int i = 0; i < 8; ++i) {
        s1acc[i] += v[i];
        s2acc[i] = fmaf(v[i], v[i], s2acc[i]);
      }
    }
  }
  // stats: reduce across nodes/groups (lane bits 4,5); lanes 0 (h=0) and 1 (h=1) hold sums.
#pragma unroll
  for (int i = 0; i < 8; ++i) {
    s1acc[i] += __shfl_xor(s1acc[i], 16);
    s1acc[i] += __shfl_xor(s1acc[i], 32);
    s2acc[i] += __shfl_xor(s2acc[i], 16);
    s2acc[i] += __shfl_xor(s2acc[i], 32);
  }
  __shared__ float sh[4][32];
  if (lane < 2) {
#pragma unroll
    for (int i = 0; i < 8; ++i) {
      sh[wave][h * 8 + i] = s1acc[i];
      sh[wave][16 + h * 8 + i] = s2acc[i];
    }
  }
  __syncthreads();
  if (t < 32) {
    float v = sh[0][t] + sh[1][t] + sh[2][t] + sh[3][t];
    if (t < 16)
      atomicAdd(&stats[p * 16 + t], v);
    else
      atomicAdd(&stats[128 + p * 16 + (t - 16)], v);
  }
}

// Final standalone norm (layer 2): bf16 col-blocked AGG -> fp32 row-major d_out.
__global__ __launch_bounds__(256) void k_norm(const unsigned* __restrict__ AGGcb,
                                              const float* __restrict__ stats,
                                              const float* __restrict__ bias,
                                              const float* __restrict__ gamma,
                                              const float* __restrict__ beta,
                                              const float* __restrict__ alpha,
                                              float* __restrict__ OUT, int N, int ROWS,
                                              float invN) {
  int i = blockIdx.x * 256 + threadIdx.x;  // 4-col chunk index over row-major out
  if (i >= N * 32) return;
  int row = i >> 5, c4 = i & 31;
  int blk = c4 >> 2, off = (2 * c4) & 7;
  uint2 u = *(const uint2*)(AGGcb + ((size_t)blk * ROWS + row) * 8 + off);
  float vv[4] = {blo(u.x), bhi(u.x), blo(u.y), bhi(u.y)};
  float ov[4];
#pragma unroll
  for (int j = 0; j < 4; ++j) {
    int c = c4 * 4 + j;
    float s1 = stats[c] * invN, s2 = stats[128 + c] * invN;
    float b = bias[c], a = alpha[c], g = gamma[c], be = beta[c];
    float mu = s1 + b;
    float E2 = s2 + 2.f * b * s1 + b * b;
    float var = E2 - (2.f * a - a * a) * mu * mu;
    float A = g * rsqrtf(var + EPS_GN);
    float B = be - A * a * mu + A * b;
    float o = fmaf(A, vv[j], B);
    ov[j] = o > 0.f ? o : 0.f;
  }
  ((float4*)OUT)[i] = make_float4(ov[0], ov[1], ov[2], ov[3]);
}

// ---------------- Launch ----------------

extern "C" void kernel_launch(void* const* d_in, const int* in_sizes, int n_in,
                              void* d_out, int out_size, void* d_ws, size_t ws_size,
                              hipStream_t stream) {
  const float* x = (const float*)d_in[0];
  const int* ei = (const int*)d_in[1];
  const float* W0 = (const float*)d_in[2];
  const float* b0 = (const float*)d_in[3];
  const float* W12 = (const float*)d_in[4];
  const float* b12 = (const float*)d_in[5];
  const float* gamma = (const float*)d_in[6];
  const float* beta = (const float*)d_in[7];
  const float* alpha = (const float*)d_in[8];
  float* out = (float*)d_out;

  int N = in_sizes[0] / 4;
  int E = in_sizes[1] / 2;
  int ROWS = N + 1;
  const int* srcArr = ei;
  const int* dstArr = ei + E;

  char* w = (char*)d_ws;
  auto alloc = [&](size_t bytes) {
    char* p = w;
    w += (bytes + 255) & ~(size_t)255;
    return p;
  };
  int* cnt = (int*)alloc((size_t)N * 4);
  float* stats = (float*)alloc(3 * 256 * 4);  // [layer][sum(128)|sumsq(128)] - adjacent to cnt
  int* rs = (int*)alloc(((size_t)N + 1) * 4);
  int* cursor = (int*)alloc((size_t)N * 4);
  int* bsum = (int*)alloc(512);
  int* boff = (int*)alloc(512);
  unsigned short* WbT = (unsigned short*)alloc(2 * 16384 * 2);        // bf16 W^T, both layers
  int* csrp = (int*)alloc(((size_t)E + 8 * (size_t)N + 2048) * 4);   // padded CSR + tail
  float* dinv = (float*)alloc((size_t)N * 4);
  unsigned* Hcb = (unsigned*)alloc((size_t)ROWS * 64 * 4);    // bf16 Hs, col-blocked
  unsigned* AGGcb = (unsigned*)alloc((size_t)ROWS * 64 * 4);  // bf16 agg, col-blocked

  // zero cnt + all stats (contiguous region)
  size_t zlen = (size_t)((char*)stats - (char*)cnt) + 3 * 256 * 4;
  hipMemsetAsync(cnt, 0, zlen, stream);

  int nblk = (N + 1023) / 1024;
  k_wt<<<128, 256, 0, stream>>>(W12, WbT);
  k_count_p<<<2048, 256, 0, stream>>>(dstArr, cnt, E, N);
  k_scan1<<<nblk, 256, 0, stream>>>(cnt, rs, bsum, N);
  k_scan2<<<1, 256, 0, stream>>>(bsum, boff, nblk);
  k_finalize<<<(N + 255) / 256, 256, 0, stream>>>(cnt, boff, rs, cursor, dinv, Hcb, csrp, N, E,
                                                  ROWS);
  k_fill_p<<<2048, 256, 0, stream>>>(srcArr, dstArr, cursor, csrp, E, N);

  float invN = 1.0f / (float)N;
  int gGemm = (N + 63) / 64;

  // Layer 0
  k_gemm0<<<(N + 3) / 4, 256, 0, stream>>>(x, W0, dinv, Hcb, N, ROWS);
  k_gather_cb<<<2048, 256, 0, stream>>>(Hcb, rs, csrp, dinv, AGGcb, stats, N, ROWS);
  // Layer 1 (norm of layer 0 fused into A-fragment build)
  k_gemm_mfma<<<gGemm, 256, 0, stream>>>(AGGcb, WbT, stats, b0, gamma, beta, alpha, dinv, Hcb, N,
                                         ROWS, invN);
  k_gather_cb<<<2048, 256, 0, stream>>>(Hcb, rs, csrp, dinv, AGGcb, stats + 256, N, ROWS);
  // Layer 2
  k_gemm_mfma<<<gGemm, 256, 0, stream>>>(AGGcb, WbT + 16384, stats + 256, b12, gamma + 128,
                                         beta + 128, alpha + 128, dinv, Hcb, N, ROWS, invN);
  k_gather_cb<<<2048, 256, 0, stream>>>(Hcb, rs, csrp, dinv, AGGcb, stats + 512, N, ROWS);
  // Final norm -> out
  k_norm<<<(N * 32 + 255) / 256, 256, 0, stream>>>(AGGcb, stats + 512, b12 + 128, gamma + 256,
                                                   beta + 256, alpha + 256, out, N, ROWS, invN);
}

// Round 10
// 609.832 us; speedup vs baseline: 1.3707x; 1.1425x over previous
//
#include <hip/hip_runtime.h>

// ConventionalGNN: 3x (GCNConv -> GraphNorm -> ReLU), N=100000 nodes, E=1.6M edges, D=128.
// Hs = dinv*h stored FP16 packed; AGG[n] = dinv[n]*(sum Hs[src] + Hs[n]), stored fp16.
// H and AGG are COLUMN-BLOCKED: 8 blocks x 16 cols (32B/row); block p -> XCD p (blockIdx&7),
// per-XCD gather working set = 3.2MB, L2-resident.
// PADDED CSR (byte offsets, slot0=self, pads->zero row N): gather inner loop = 4x
// v_pk_add_f16 + 1 cndmask + saddr+voffset load per batch; csr 2 batches ahead, H ping-pong.

#define EPS_GN 1e-5f

typedef __attribute__((ext_vector_type(8))) _Float16 f16x8;
typedef __attribute__((ext_vector_type(2))) _Float16 f16x2;
typedef __attribute__((ext_vector_type(4))) float f32x4;

template <typename T, typename U>
__device__ __forceinline__ T bc(U u) {
  return __builtin_bit_cast(T, u);
}
// pack 2 floats -> packed fp16 dword (RTZ, 1 instr)
__device__ __forceinline__ unsigned pkh(float x, float y) {
  return bc<unsigned>(__builtin_amdgcn_cvt_pkrtz(x, y));
}

// ---------------- CSR build ----------------

__global__ __launch_bounds__(256) void k_count_p(const int* __restrict__ dst,
                                                 int* __restrict__ cnt, int E, int N) {
  int p = blockIdx.x & 7;
  int lo = (int)((long long)N * p >> 3), hi = (int)((long long)N * (p + 1) >> 3);
  int stride = (gridDim.x >> 3) * 256;
  for (int e = (blockIdx.x >> 3) * 256 + threadIdx.x; e < E; e += stride) {
    int d = dst[e];
    if (d >= lo && d < hi) atomicAdd(&cnt[d], 1);
  }
}

// Scan of PADDED slot counts pc = (cnt+8)&~7 (self + edges + pad to 8).
__global__ __launch_bounds__(256) void k_scan1(const int* __restrict__ cnt,
                                               int* __restrict__ rs,
                                               int* __restrict__ bsum, int N) {
  __shared__ int s[256];
  int t = threadIdx.x;
  int base = blockIdx.x * 1024 + t * 4;
  int c0 = (base + 0 < N) ? ((cnt[base + 0] + 8) & ~7) : 0;
  int c1 = (base + 1 < N) ? ((cnt[base + 1] + 8) & ~7) : 0;
  int c2 = (base + 2 < N) ? ((cnt[base + 2] + 8) & ~7) : 0;
  int c3 = (base + 3 < N) ? ((cnt[base + 3] + 8) & ~7) : 0;
  int tsum = c0 + c1 + c2 + c3;
  s[t] = tsum;
  __syncthreads();
  for (int off = 1; off < 256; off <<= 1) {
    int v = (t >= off) ? s[t - off] : 0;
    __syncthreads();
    s[t] += v;
    __syncthreads();
  }
  int excl = s[t] - tsum;
  if (t == 255) bsum[blockIdx.x] = s[255];
  int e0 = excl, e1 = e0 + c0, e2 = e1 + c1, e3 = e2 + c2;
  if (base + 0 < N) rs[base + 0] = e0;
  if (base + 1 < N) rs[base + 1] = e1;
  if (base + 2 < N) rs[base + 2] = e2;
  if (base + 3 < N) rs[base + 3] = e3;
}

__global__ __launch_bounds__(256) void k_scan2(const int* __restrict__ bsum,
                                               int* __restrict__ boff, int nblk) {
  __shared__ int s[256];
  int t = threadIdx.x;
  int v0 = (t < nblk) ? bsum[t] : 0;
  s[t] = v0;
  __syncthreads();
  for (int off = 1; off < 256; off <<= 1) {
    int v = (t >= off) ? s[t - off] : 0;
    __syncthreads();
    s[t] += v;
    __syncthreads();
  }
  if (t < nblk) boff[t] = s[t] - v0;
}

// Finalize: rs -> padded slot offsets; cursor = rs+1; dinv; self slot (byte offset i*32);
// pad slots = N*32; zero-row N of Hcb; 1024-dword csrp tail = N*32 (safe lookahead).
__global__ __launch_bounds__(256) void k_finalize(const int* __restrict__ cnt,
                                                  const int* __restrict__ boff,
                                                  int* __restrict__ rs,
                                                  int* __restrict__ cursor,
                                                  float* __restrict__ dinv,
                                                  unsigned* __restrict__ Hcb,
                                                  int* __restrict__ csrp, int N, int E,
                                                  int ROWS) {
  __shared__ int sTail;
  int i = blockIdx.x * 256 + threadIdx.x;
  int NB = N * 32;
  if (i < 64) Hcb[((size_t)(i >> 3) * ROWS + N) * 8 + (i & 7)] = 0u;
  if (i < N) {
    int v = rs[i] + boff[i >> 10];
    int c = cnt[i];
    int pc = (c + 8) & ~7;
    rs[i] = v;
    cursor[i] = v + 1;
    dinv[i] = rsqrtf((float)c + 1.0f);
    csrp[v] = i * 32;  // self slot (byte offset)
    for (int k = v + 1 + c; k < v + pc; ++k) csrp[k] = NB;  // pads -> zero row
    if (i == N - 1) {
      rs[N] = v + pc;
      sTail = v + pc;
    }
  }
  __syncthreads();
  if (blockIdx.x == gridDim.x - 1) {
    int base = sTail;
    for (int k = threadIdx.x; k < 1024; k += 256) csrp[base + k] = NB;
  }
}

__global__ __launch_bounds__(256) void k_fill_p(const int* __restrict__ src,
                                                const int* __restrict__ dst,
                                                int* __restrict__ cursor,
                                                int* __restrict__ csrp, int E, int N) {
  int p = blockIdx.x & 7;
  int lo = (int)((long long)N * p >> 3), hi = (int)((long long)N * (p + 1) >> 3);
  int stride = (gridDim.x >> 3) * 256;
  for (int e = (blockIdx.x >> 3) * 256 + threadIdx.x; e < E; e += stride) {
    int d = dst[e];
    if (d >= lo && d < hi) {
      int pos = atomicAdd(&cursor[d], 1);
      csrp[pos] = src[e] << 5;  // byte offset
    }
  }
}

// ---------------- Weight transpose (once per call) ----------------

// WbT[layer][n][k] = fp16(W12[layer][k][n]); output-coalesced.
__global__ __launch_bounds__(256) void k_wt(const float* __restrict__ W12,
                                            _Float16* __restrict__ WbT) {
  int o = blockIdx.x * 256 + threadIdx.x;  // [0, 2*16384)
  int layer = o >> 14, r = o & 16383;
  int n = r >> 7, k = r & 127;
  WbT[o] = (_Float16)W12[layer * 16384 + k * 128 + n];
}

// ---------------- Layer kernels ----------------

// Hs(fp16, col-blocked) = dinv * (X @ W0). 4 rows/block; thread = 1 row x 2 cols.
__global__ __launch_bounds__(256) void k_gemm0(const float* __restrict__ X,
                                               const float* __restrict__ W,
                                               const float* __restrict__ dinv,
                                               unsigned* __restrict__ Hcb, int N, int ROWS) {
  __shared__ float Ws[4 * 128];
  int t = threadIdx.x;
  if (t < 128) {
    Ws[t] = W[t];
    Ws[128 + t] = W[128 + t];
    Ws[256 + t] = W[256 + t];
    Ws[384 + t] = W[384 + t];
  }
  __syncthreads();
  int r = t >> 6, l = t & 63;
  int row = blockIdx.x * 4 + r;
  if (row >= N) return;
  float4 xv = ((const float4*)X)[row];
  float di = dinv[row];
  int c0 = 2 * l, c1 = 2 * l + 1;
  float v0 = xv.x * Ws[c0] + xv.y * Ws[128 + c0] + xv.z * Ws[256 + c0] + xv.w * Ws[384 + c0];
  float v1 = xv.x * Ws[c1] + xv.y * Ws[128 + c1] + xv.z * Ws[256 + c1] + xv.w * Ws[384 + c1];
  Hcb[((size_t)(l >> 3) * ROWS + row) * 8 + (l & 7)] = pkh(di * v0, di * v1);
}

// Hs(fp16, col-blocked) = dinv * (relu(norm(AGGcb)) @ W) via MFMA 16x16x32 f16.
__global__ __launch_bounds__(256, 4) void k_gemm_mfma(const unsigned* __restrict__ AGGcb,
                                                      const _Float16* __restrict__ WbT,
                                                      const float* __restrict__ stats,
                                                      const float* __restrict__ bias,
                                                      const float* __restrict__ gamma,
                                                      const float* __restrict__ beta,
                                                      const float* __restrict__ alpha,
                                                      const float* __restrict__ dinv,
                                                      unsigned* __restrict__ Hcb, int N,
                                                      int ROWS, float invN) {
  __shared__ float As[128], Bs[128];
  int t = threadIdx.x;
  if (t < 128) {
    float s1 = stats[t] * invN, s2 = stats[128 + t] * invN;
    float b = bias[t], a = alpha[t], g = gamma[t], be = beta[t];
    float mu = s1 + b;                     // mean of (agg + b)
    float E2 = s2 + 2.f * b * s1 + b * b;  // E[(agg+b)^2]
    float var = E2 - (2.f * a - a * a) * mu * mu;
    float A = g * rsqrtf(var + EPS_GN);
    As[t] = A;
    Bs[t] = be - A * a * mu + A * b;  // normed = A*agg + B
  }
  __syncthreads();
  int wv = t >> 6, l = t & 63;
  int r0 = blockIdx.x * 64 + wv * 16;
  if (r0 >= N) return;
  int m = l & 15, kb = l >> 4;

  f32x4 acc[8];
#pragma unroll
  for (int nt = 0; nt < 8; ++nt) acc[nt] = (f32x4){0.f, 0.f, 0.f, 0.f};

#pragma unroll
  for (int ks = 0; ks < 4; ++ks) {
    int k0 = ks * 32 + kb * 8;
    const uint4* pa = (const uint4*)(AGGcb + ((size_t)(2 * ks + (kb >> 1)) * ROWS + r0 + m) * 8 +
                                     (kb & 1) * 4);
    uint4 a_raw = pa[0];
    float4 A0 = *reinterpret_cast<const float4*>(&As[k0]);
    float4 A1 = *reinterpret_cast<const float4*>(&As[k0 + 4]);
    float4 B0 = *reinterpret_cast<const float4*>(&Bs[k0]);
    float4 B1 = *reinterpret_cast<const float4*>(&Bs[k0 + 4]);
    f16x8 bf[8];
#pragma unroll
    for (int nt = 0; nt < 8; ++nt)
      bf[nt] = *reinterpret_cast<const f16x8*>(WbT + (size_t)(nt * 16 + m) * 128 + k0);
    unsigned uu[4] = {a_raw.x, a_raw.y, a_raw.z, a_raw.w};
    float xr[8];
#pragma unroll
    for (int i = 0; i < 4; ++i) {
      f16x2 hp = bc<f16x2>(uu[i]);
      xr[2 * i] = (float)hp[0];
      xr[2 * i + 1] = (float)hp[1];
    }
    float Aa[8] = {A0.x, A0.y, A0.z, A0.w, A1.x, A1.y, A1.z, A1.w};
    float Bb[8] = {B0.x, B0.y, B0.z, B0.w, B1.x, B1.y, B1.z, B1.w};
    float xs[8];
#pragma unroll
    for (int j = 0; j < 8; ++j) {
      float v = fmaf(Aa[j], xr[j], Bb[j]);
      xs[j] = v > 0.f ? v : 0.f;
    }
    uint4 au;
    au.x = pkh(xs[0], xs[1]);
    au.y = pkh(xs[2], xs[3]);
    au.z = pkh(xs[4], xs[5]);
    au.w = pkh(xs[6], xs[7]);
    f16x8 af = bc<f16x8>(au);
#pragma unroll
    for (int nt = 0; nt < 8; ++nt)
      acc[nt] = __builtin_amdgcn_mfma_f32_16x16x32_f16(af, bf[nt], acc[nt], 0, 0, 0);
  }

  float dn[4];
#pragma unroll
  for (int r = 0; r < 4; ++r) dn[r] = dinv[r0 + kb * 4 + r];
  bool even = (l & 1) == 0;
#pragma unroll
  for (int nt = 0; nt < 8; ++nt) {
#pragma unroll
    for (int r = 0; r < 4; ++r) {
      float v = acc[nt][r] * dn[r];
      float pv = __shfl_xor(v, 1);
      if (even) {
        unsigned word = pkh(v, pv);
        Hcb[((size_t)nt * ROWS + r0 + kb * 4 + r) * 8 + (m >> 1)] = word;
      }
    }
  }
}

// Column-blocked gather v4 (fp16 packed adds): partition p = blockIdx&7 -> cols [16p,16p+16).
// Wave = 4 nodes (g) x 8 slots (e) x 2 half-rows (h); lane loads uint4 (16B = 8 fp16).
// csrp holds byte offsets; H address = uniform base + (off + h*16) voffset.
// Accumulate with v_pk_add_f16 (4/batch); csr 2 batches ahead; H ping-pong, unroll-2.
__global__ __launch_bounds__(256) void k_gather_cb(const unsigned* __restrict__ Hcb,
                                                   const int* __restrict__ rsp,
                                                   const int* __restrict__ csrp,
                                                   const float* __restrict__ dinv,
                                                   unsigned* __restrict__ AGGcb,
                                                   float* __restrict__ stats, int N, int ROWS) {
  int t = threadIdx.x;
  int wave = t >> 6, lane = t & 63;
  int g = lane >> 4, e = (lane >> 1) & 7, h = lane & 1;
  int p = blockIdx.x & 7;
  const unsigned char* HpB = (const unsigned char*)Hcb + (size_t)p * ROWS * 32;  // uniform
  uint4* Ap4 = (uint4*)(AGGcb + (size_t)p * ROWS * 8);
  int NB = N * 32;
  int ho = h * 16;
  int q = blockIdx.x >> 3;
  int nstride = (gridDim.x >> 3) * 16;  // blocks/partition * 4 waves * 4 nodes
  float s1acc[8], s2acc[8];
#pragma unroll
  for (int i = 0; i < 8; ++i) s1acc[i] = s2acc[i] = 0.f;

  for (int n0 = (q * 4 + wave) * 4; n0 < N; n0 += nstride) {
    int n = n0 + g;  // N % 4 == 0 -> n < N
    int j0 = rsp[n], j1 = rsp[n + 1];
    int nb = (j1 - j0) >> 3;  // padded batch count (>= 1)
    int ml = nb;
    ml = max(ml, __shfl_xor(ml, 16));
    ml = max(ml, __shfl_xor(ml, 32));  // wave-uniform batch count
    f16x2 acc[4];
#pragma unroll
    for (int i = 0; i < 4; ++i) acc[i] = (f16x2){(_Float16)0, (_Float16)0};

    const int* cp = csrp + j0 + e;  // lane slot pointer; batch b at cp[b*8]
    auto hload = [&](int c, int b) -> uint4 {
      int ce = (b < nb) ? c : NB;  // beyond own batches -> zero row
      return *(const uint4*)(HpB + (unsigned)(ce + ho));
    };
    int c0 = cp[0], c1 = cp[8];
    uint4 hA = hload(c0, 0);
    uint4 hB = hload(c1, 1);
    int c2 = cp[16], c3 = cp[24];
    const int* cpp = cp + 32;  // batch 4

    for (int b = 0; b < ml; b += 2) {
      acc[0] += bc<f16x2>(hA.x);
      acc[1] += bc<f16x2>(hA.y);
      acc[2] += bc<f16x2>(hA.z);
      acc[3] += bc<f16x2>(hA.w);
      hA = hload(c2, b + 2);
      c2 = cpp[0];
      if (b + 1 < ml) {  // wave-uniform (scalar) branch
        acc[0] += bc<f16x2>(hB.x);
        acc[1] += bc<f16x2>(hB.y);
        acc[2] += bc<f16x2>(hB.z);
        acc[3] += bc<f16x2>(hB.w);
        hB = hload(c3, b + 3);
        c3 = cpp[8];
      }
      cpp += 16;
    }
    // reduce across the 8 edge-slots (lane bits 1..3), packed
#pragma unroll
    for (int i = 0; i < 4; ++i) {
      acc[i] += bc<f16x2>((unsigned)__shfl_xor(bc<int>(acc[i]), 2));
      acc[i] += bc<f16x2>((unsigned)__shfl_xor(bc<int>(acc[i]), 4));
      acc[i] += bc<f16x2>((unsigned)__shfl_xor(bc<int>(acc[i]), 8));
    }
    if (e == 0) {
      float dn = dinv[n];
      float v[8];
#pragma unroll
      for (int i = 0; i < 4; ++i) {
        v[2 * i] = (float)acc[i][0] * dn;
        v[2 * i + 1] = (float)acc[i][1] * dn;
      }
      uint4 wv;
      unsigned* wp = (unsigned*)&wv;
#pragma unroll
      for (int i = 0; i < 4; ++i) wp[i] = pkh(v[2 * i], v[2 * i + 1]);
      Ap4[(size_t)n * 2 + h] = wv;
#pragma unroll
      for (int i = 0; i < 8; ++i) {
        s1acc[i] += v[i];
        s2acc[i] = fmaf(v[i], v[i], s2acc[i]);
      }
    }
  }
  // stats: reduce across nodes/groups (lane bits 4,5); lanes 0 (h=0) and 1 (h=1) hold sums.
#pragma unroll
  for (int i = 0; i < 8; ++i) {
    s1acc[i] += __shfl_xor(s1acc[i], 16);
    s1acc[i] += __shfl_xor(s1acc[i], 32);
    s2acc[i] += __shfl_xor(s2acc[i], 16);
    s2acc[i] += __shfl_xor(s2acc[i], 32);
  }
  __shared__ float sh[4][32];
  if (lane < 2) {
#pragma unroll
    for (int i = 0; i < 8; ++i) {
      sh[wave][h * 8 + i] = s1acc[i];
      sh[wave][16 + h * 8 + i] = s2acc[i];
    }
  }
  __syncthreads();
  if (t < 32) {
    float v = sh[0][t] + sh[1][t] + sh[2][t] + sh[3][t];
    if (t < 16)
      atomicAdd(&stats[p * 16 + t], v);
    else
      atomicAdd(&stats[128 + p * 16 + (t - 16)], v);
  }
}

// Final standalone norm (layer 2): fp16 col-blocked AGG -> fp32 row-major d_out.
__global__ __launch_bounds__(256) void k_norm(const unsigned* __restrict__ AGGcb,
                                              const float* __restrict__ stats,
                                              const float* __restrict__ bias,
                                              const float* __restrict__ gamma,
                                              const float* __restrict__ beta,
                                              const float* __restrict__ alpha,
                                              float* __restrict__ OUT, int N, int ROWS,
                                              float invN) {
  int i = blockIdx.x * 256 + threadIdx.x;  // 4-col chunk index over row-major out
  if (i >= N * 32) return;
  int row = i >> 5, c4 = i & 31;
  int blk = c4 >> 2, off = (2 * c4) & 7;
  uint2 u = *(const uint2*)(AGGcb + ((size_t)blk * ROWS + row) * 8 + off);
  f16x2 p0 = bc<f16x2>(u.x), p1 = bc<f16x2>(u.y);
  float vv[4] = {(float)p0[0], (float)p0[1], (float)p1[0], (float)p1[1]};
  float ov[4];
#pragma unroll
  for (int j = 0; j < 4; ++j) {
    int c = c4 * 4 + j;
    float s1 = stats[c] * invN, s2 = stats[128 + c] * invN;
    float b = bias[c], a = alpha[c], g = gamma[c], be = beta[c];
    float mu = s1 + b;
    float E2 = s2 + 2.f * b * s1 + b * b;
    float var = E2 - (2.f * a - a * a) * mu * mu;
    float A = g * rsqrtf(var + EPS_GN);
    float B = be - A * a * mu + A * b;
    float o = fmaf(A, vv[j], B);
    ov[j] = o > 0.f ? o : 0.f;
  }
  ((float4*)OUT)[i] = make_float4(ov[0], ov[1], ov[2], ov[3]);
}

// ---------------- Launch ----------------

extern "C" void kernel_launch(void* const* d_in, const int* in_sizes, int n_in,
                              void* d_out, int out_size, void* d_ws, size_t ws_size,
                              hipStream_t stream) {
  const float* x = (const float*)d_in[0];
  const int* ei = (const int*)d_in[1];
  const float* W0 = (const float*)d_in[2];
  const float* b0 = (const float*)d_in[3];
  const float* W12 = (const float*)d_in[4];
  const float* b12 = (const float*)d_in[5];
  const float* gamma = (const float*)d_in[6];
  const float* beta = (const float*)d_in[7];
  const float* alpha = (const float*)d_in[8];
  float* out = (float*)d_out;

  int N = in_sizes[0] / 4;
  int E = in_sizes[1] / 2;
  int ROWS = N + 1;
  const int* srcArr = ei;
  const int* dstArr = ei + E;

  char* w = (char*)d_ws;
  auto alloc = [&](size_t bytes) {
    char* p = w;
    w += (bytes + 255) & ~(size_t)255;
    return p;
  };
  int* cnt = (int*)alloc((size_t)N * 4);
  float* stats = (float*)alloc(3 * 256 * 4);  // [layer][sum(128)|sumsq(128)] - adjacent to cnt
  int* rs = (int*)alloc(((size_t)N + 1) * 4);
  int* cursor = (int*)alloc((size_t)N * 4);
  int* bsum = (int*)alloc(512);
  int* boff = (int*)alloc(512);
  _Float16* WbT = (_Float16*)alloc(2 * 16384 * 2);                  // fp16 W^T, both layers
  int* csrp = (int*)alloc(((size_t)E + 8 * (size_t)N + 2048) * 4);  // padded CSR + tail
  float* dinv = (float*)alloc((size_t)N * 4);
  unsigned* Hcb = (unsigned*)alloc((size_t)ROWS * 64 * 4);    // fp16 Hs, col-blocked
  unsigned* AGGcb = (unsigned*)alloc((size_t)ROWS * 64 * 4);  // fp16 agg, col-blocked

  // zero cnt + all stats (contiguous region)
  size_t zlen = (size_t)((char*)stats - (char*)cnt) + 3 * 256 * 4;
  hipMemsetAsync(cnt, 0, zlen, stream);

  int nblk = (N + 1023) / 1024;
  k_wt<<<128, 256, 0, stream>>>(W12, WbT);
  k_count_p<<<2048, 256, 0, stream>>>(dstArr, cnt, E, N);
  k_scan1<<<nblk, 256, 0, stream>>>(cnt, rs, bsum, N);
  k_scan2<<<1, 256, 0, stream>>>(bsum, boff, nblk);
  k_finalize<<<(N + 255) / 256, 256, 0, stream>>>(cnt, boff, rs, cursor, dinv, Hcb, csrp, N, E,
                                                  ROWS);
  k_fill_p<<<2048, 256, 0, stream>>>(srcArr, dstArr, cursor, csrp, E, N);

  float invN = 1.0f / (float)N;
  int gGemm = (N + 63) / 64;

  // Layer 0
  k_gemm0<<<(N + 3) / 4, 256, 0, stream>>>(x, W0, dinv, Hcb, N, ROWS);
  k_gather_cb<<<2048, 256, 0, stream>>>(Hcb, rs, csrp, dinv, AGGcb, stats, N, ROWS);
  // Layer 1 (norm of layer 0 fused into A-fragment build)
  k_gemm_mfma<<<gGemm, 256, 0, stream>>>(AGGcb, WbT, stats, b0, gamma, beta, alpha, dinv, Hcb, N,
                                         ROWS, invN);
  k_gather_cb<<<2048, 256, 0, stream>>>(Hcb, rs, csrp, dinv, AGGcb, stats + 256, N, ROWS);
  // Layer 2
  k_gemm_mfma<<<gGemm, 256, 0, stream>>>(AGGcb, WbT + 16384, stats + 256, b12, gamma + 128,
                                         beta + 128, alpha + 128, dinv, Hcb, N, ROWS, invN);
  k_gather_cb<<<2048, 256, 0, stream>>>(Hcb, rs, csrp, dinv, AGGcb, stats + 512, N, ROWS);
  // Final norm -> out
  k_norm<<<(N * 32 + 255) / 256, 256, 0, stream>>>(AGGcb, stats + 512, b12 + 128, gamma + 256,
                                                   beta + 256, alpha + 256, out, N, ROWS, invN);
}